// Round 6
// baseline (601.555 us; speedup 1.0000x reference)
//
#include <hip/hip_runtime.h>

#define B_DIM 512
#define R_DIM 1152
#define C_DIM 10
#define O_DIM 16
#define CO    160   // C*O
#define NCO4  40    // CO/4

// ---------------------------------------------------------------------------
// u_hat[b,r,c,o] = sum_i W[r,c,o,i] * x[b,r,i]  (+ s1 partials, optional store)
// No LDS/syncs: each thread's 32 W floats are contiguous (128 B, L2-resident
// across b-tiles); x rows dedup'd by the coalescer (40 lanes same address).
// grid (64 r-chunks of 18, 16 b-tiles of 32), block 320 = 8 b-lanes x 40 co4
// ---------------------------------------------------------------------------
template<bool STORE_U>
__global__ __launch_bounds__(320)
void k_uhat(const float* __restrict__ x, const float* __restrict__ W,
            float* __restrict__ u, float* __restrict__ part1)
{
    const int t    = threadIdx.x;
    const int co4  = t % NCO4;
    const int slot = t / NCO4;       // b-lane 0..7
    const int rc   = blockIdx.x;
    const int b0   = blockIdx.y * 32;
    const int r0   = rc * 18;

    const float* wp = W + (size_t)r0 * 1280 + co4 * 32;
    const float* xp = x + ((size_t)(b0 + slot) * R_DIM + r0) * 8;
    float*       up = u + ((size_t)(b0 + slot) * R_DIM + r0) * CO + co4 * 4;

    float4 sacc[4];
    #pragma unroll
    for (int i = 0; i < 4; ++i) sacc[i] = make_float4(0.f, 0.f, 0.f, 0.f);

    for (int rr = 0; rr < 18; ++rr) {
        float w[32];                                  // w[oo*8+i]
        #pragma unroll
        for (int k = 0; k < 8; ++k)
            *reinterpret_cast<float4*>(&w[k * 4]) =
                *reinterpret_cast<const float4*>(wp + k * 4);

        #pragma unroll
        for (int bb = 0; bb < 4; ++bb) {
            const float* xq = xp + bb * (8 * R_DIM * 8);   // b += 8
            float4 xa = *reinterpret_cast<const float4*>(xq);
            float4 xb = *reinterpret_cast<const float4*>(xq + 4);
            float xr[8] = {xa.x, xa.y, xa.z, xa.w, xb.x, xb.y, xb.z, xb.w};
            float4 acc = make_float4(0.f, 0.f, 0.f, 0.f);
            #pragma unroll
            for (int i = 0; i < 8; ++i) {
                acc.x = fmaf(w[i],      xr[i], acc.x);
                acc.y = fmaf(w[8 + i],  xr[i], acc.y);
                acc.z = fmaf(w[16 + i], xr[i], acc.z);
                acc.w = fmaf(w[24 + i], xr[i], acc.w);
            }
            if constexpr (STORE_U)
                *reinterpret_cast<float4*>(up + bb * (8 * R_DIM * CO)) = acc;
            sacc[bb].x += acc.x; sacc[bb].y += acc.y;
            sacc[bb].z += acc.z; sacc[bb].w += acc.w;
        }
        wp += 1280; xp += 8; up += CO;
    }

    #pragma unroll
    for (int bb = 0; bb < 4; ++bb) {
        const int b = b0 + bb * 8 + slot;
        *reinterpret_cast<float4*>(
            part1 + ((size_t)rc * B_DIM + b) * CO + co4 * 4) = sacc[bb];
    }
}

// ---------------------------------------------------------------------------
// Reduce nchunk partials -> s, scale, squash over O=16, write dst (v or out).
// 81920 outputs: grid 256, block 320; 16-lane groups = o 0..15 of one (b,c).
// ---------------------------------------------------------------------------
__global__ __launch_bounds__(320)
void k_vred(const float* __restrict__ part, float* __restrict__ dst,
            int nchunk, float scale)
{
    const int idx = blockIdx.x * 320 + threadIdx.x;
    const int b = idx / CO, co = idx % CO;
    float s = 0.f;
    for (int k = 0; k < nchunk; ++k)
        s += part[((size_t)k * B_DIM + b) * CO + co];
    s *= scale;
    float sq = s * s;
    sq += __shfl_xor(sq, 1);
    sq += __shfl_xor(sq, 2);
    sq += __shfl_xor(sq, 4);
    sq += __shfl_xor(sq, 8);
    float v = s * (sq / (1.f + sq)) / sqrtf(sq + 1e-8f);
    dst[idx] = v;
}

// ---------------------------------------------------------------------------
// Routing pass (materialized u). logits = dot(u, vl) where vl = v1 (pass 1)
// or v1+v2 (pass 2) — the b_ij buffer is algebraically eliminated.
// grid (512 b, 8 r-chunks of 144), block 320 = 8 r-slots x 40 co4.
// quad invariant: co4 == t (mod 4), so shfl_xor(1|2) reduces over o in (c).
// al is double-buffered so ONE barrier per iteration suffices: a wave
// re-writes buffer p at iter it+2 only after passing barrier(it+1), which
// all waves reach only after their (program-order-earlier) reads of p.
// ---------------------------------------------------------------------------
template<int PASS>
__global__ __launch_bounds__(320)
void k_route(const float* __restrict__ u, const float* __restrict__ v1,
             const float* __restrict__ v2, float* __restrict__ spart)
{
    __shared__ float vl[CO];
    __shared__ float al[2][8][C_DIM];
    __shared__ float sred[8][CO];

    const int t    = threadIdx.x;
    const int co4  = t % NCO4;
    const int slot = t / NCO4;       // r_local 0..7
    const int c    = co4 >> 2;
    const int o4   = co4 & 3;
    const int b    = blockIdx.x;
    const int r0   = blockIdx.y * 144;

    if (t < NCO4) {
        float4 a = *reinterpret_cast<const float4*>(v1 + (size_t)b * CO + t * 4);
        if constexpr (PASS == 2) {
            float4 bv = *reinterpret_cast<const float4*>(v2 + (size_t)b * CO + t * 4);
            a.x += bv.x; a.y += bv.y; a.z += bv.z; a.w += bv.w;
        }
        *reinterpret_cast<float4*>(&vl[t * 4]) = a;
    }
    float4 sacc = make_float4(0.f, 0.f, 0.f, 0.f);
    __syncthreads();

    for (int it = 0; it < 18; ++it) {
        const int r = r0 + it * 8 + slot;
        const int pb = it & 1;
        const float4 u4 = *reinterpret_cast<const float4*>(
            u + ((size_t)b * R_DIM + r) * CO + co4 * 4);
        const float4 vv = *reinterpret_cast<const float4*>(&vl[co4 * 4]);
        float p = u4.x * vv.x + u4.y * vv.y + u4.z * vv.z + u4.w * vv.w;
        p += __shfl_xor(p, 1);
        p += __shfl_xor(p, 2);       // all 4 quad lanes hold logit[c]

        if (o4 == 0) al[pb][slot][c] = p;
        __syncthreads();             // publish al[pb]; also WAR-safe (see hdr)

        float m = -3.4e38f;
        #pragma unroll
        for (int cc = 0; cc < C_DIM; ++cc) m = fmaxf(m, al[pb][slot][cc]);
        float Z = 0.f;
        #pragma unroll
        for (int cc = 0; cc < C_DIM; ++cc) Z += __expf(al[pb][slot][cc] - m);
        const float cij = __expf(p - m) / Z;

        sacc.x += cij * u4.x; sacc.y += cij * u4.y;
        sacc.z += cij * u4.z; sacc.w += cij * u4.w;
    }

    // reduce s over the 8 r-slots -> spart chunk
    *reinterpret_cast<float4*>(&sred[slot][co4 * 4]) = sacc;
    __syncthreads();
    if (slot < 4) {
        float4 a2 = *reinterpret_cast<float4*>(&sred[slot][co4 * 4]);
        float4 b2 = *reinterpret_cast<float4*>(&sred[slot + 4][co4 * 4]);
        a2.x += b2.x; a2.y += b2.y; a2.z += b2.z; a2.w += b2.w;
        *reinterpret_cast<float4*>(&sred[slot][co4 * 4]) = a2;
    }
    __syncthreads();
    if (slot < 2) {
        float4 a2 = *reinterpret_cast<float4*>(&sred[slot][co4 * 4]);
        float4 b2 = *reinterpret_cast<float4*>(&sred[slot + 2][co4 * 4]);
        a2.x += b2.x; a2.y += b2.y; a2.z += b2.z; a2.w += b2.w;
        *reinterpret_cast<float4*>(&sred[slot][co4 * 4]) = a2;
    }
    __syncthreads();
    if (slot == 0) {
        float4 a2 = *reinterpret_cast<float4*>(&sred[0][co4 * 4]);
        float4 b2 = *reinterpret_cast<float4*>(&sred[1][co4 * 4]);
        a2.x += b2.x; a2.y += b2.y; a2.z += b2.z; a2.w += b2.w;
        *reinterpret_cast<float4*>(
            spart + ((size_t)blockIdx.y * B_DIM + b) * CO + co4 * 4) = a2;
    }
}

// ---------------------------------------------------------------------------
// FALLBACK routing pass: recomputes u_hat from x,W (no u buffer in ws).
// grid (64 rc of 18 r's, 16 b-tiles of 32), block 320 = 8 b-lanes x 40 co4.
// Softmax computed non-redundantly by (bl,cc) thread mapping (320 = 32x10).
// ---------------------------------------------------------------------------
template<int PASS>
__global__ __launch_bounds__(320)
void k_route_rc(const float* __restrict__ x, const float* __restrict__ W,
                const float* __restrict__ v1, const float* __restrict__ v2,
                float* __restrict__ spart)
{
    __shared__ float vl[32][CO];     // 20 KB
    __shared__ float al[32][C_DIM];
    __shared__ float cl[32][C_DIM];

    const int t    = threadIdx.x;
    const int co4  = t % NCO4;
    const int slot = t / NCO4;       // b-lane 0..7
    const int c    = co4 >> 2;
    const int o4   = co4 & 3;
    const int rc   = blockIdx.x;
    const int b0   = blockIdx.y * 32;
    const int r0   = rc * 18;

    for (int i = t; i < 32 * NCO4; i += 320) {
        int bl = i / NCO4, q = i % NCO4;
        float4 a = *reinterpret_cast<const float4*>(v1 + (size_t)(b0 + bl) * CO + q * 4);
        if constexpr (PASS == 2) {
            float4 bv = *reinterpret_cast<const float4*>(v2 + (size_t)(b0 + bl) * CO + q * 4);
            a.x += bv.x; a.y += bv.y; a.z += bv.z; a.w += bv.w;
        }
        *reinterpret_cast<float4*>(&vl[bl][q * 4]) = a;
    }
    float4 sacc[4];
    #pragma unroll
    for (int i = 0; i < 4; ++i) sacc[i] = make_float4(0.f, 0.f, 0.f, 0.f);
    __syncthreads();

    const float* wp = W + (size_t)r0 * 1280 + co4 * 32;
    for (int rr = 0; rr < 18; ++rr) {
        float w[32];
        #pragma unroll
        for (int k = 0; k < 8; ++k)
            *reinterpret_cast<float4*>(&w[k * 4]) =
                *reinterpret_cast<const float4*>(wp + k * 4);

        float4 u4[4];
        float  p[4];
        #pragma unroll
        for (int bb = 0; bb < 4; ++bb) {
            const int bl = bb * 8 + slot;
            const float* xq = x + ((size_t)(b0 + bl) * R_DIM + r0 + rr) * 8;
            float4 xa = *reinterpret_cast<const float4*>(xq);
            float4 xb = *reinterpret_cast<const float4*>(xq + 4);
            float xr[8] = {xa.x, xa.y, xa.z, xa.w, xb.x, xb.y, xb.z, xb.w};
            float4 acc = make_float4(0.f, 0.f, 0.f, 0.f);
            #pragma unroll
            for (int i = 0; i < 8; ++i) {
                acc.x = fmaf(w[i],      xr[i], acc.x);
                acc.y = fmaf(w[8 + i],  xr[i], acc.y);
                acc.z = fmaf(w[16 + i], xr[i], acc.z);
                acc.w = fmaf(w[24 + i], xr[i], acc.w);
            }
            u4[bb] = acc;
            float4 vv = *reinterpret_cast<const float4*>(&vl[bl][co4 * 4]);
            float pp = acc.x * vv.x + acc.y * vv.y + acc.z * vv.z + acc.w * vv.w;
            pp += __shfl_xor(pp, 1);
            pp += __shfl_xor(pp, 2);
            p[bb] = pp;
        }

        __syncthreads();             // WAR on al/cl
        if (o4 == 0) {
            #pragma unroll
            for (int bb = 0; bb < 4; ++bb) al[bb * 8 + slot][c] = p[bb];
        }
        __syncthreads();
        {
            const int bl = t / C_DIM, cc = t % C_DIM;   // 320 = 32 x 10
            float m = -3.4e38f;
            #pragma unroll
            for (int c2 = 0; c2 < C_DIM; ++c2) m = fmaxf(m, al[bl][c2]);
            float Z = 0.f, e = 0.f;
            #pragma unroll
            for (int c2 = 0; c2 < C_DIM; ++c2) {
                float ee = __expf(al[bl][c2] - m);
                Z += ee;
                if (c2 == cc) e = ee;
            }
            cl[bl][cc] = e / Z;
        }
        __syncthreads();
        #pragma unroll
        for (int bb = 0; bb < 4; ++bb) {
            const float cij = cl[bb * 8 + slot][c];
            sacc[bb].x += cij * u4[bb].x; sacc[bb].y += cij * u4[bb].y;
            sacc[bb].z += cij * u4[bb].z; sacc[bb].w += cij * u4[bb].w;
        }
        wp += 1280;
    }

    #pragma unroll
    for (int bb = 0; bb < 4; ++bb) {
        const int b = b0 + bb * 8 + slot;
        *reinterpret_cast<float4*>(
            spart + ((size_t)rc * B_DIM + b) * CO + co4 * 4) = sacc[bb];
    }
}

// ---------------------------------------------------------------------------
extern "C" void kernel_launch(void* const* d_in, const int* in_sizes, int n_in,
                              void* d_out, int out_size, void* d_ws, size_t ws_size,
                              hipStream_t stream)
{
    const float* x = (const float*)d_in[0];   // [512,1152,8]
    const float* W = (const float*)d_in[1];   // [1,1152,10,16,8]
    float* out = (float*)d_out;               // [512,10,16]
    float* ws  = (float*)d_ws;

    const size_t NU = 94371840, NP64 = 5242880, NP8 = 655360, NV = 81920;
    const size_t MAIN_NEED = (NU + NP64 + 2 * NP8 + 2 * NV) * 4;      // 404.4 MB
    const size_t FB_NEED   = (3 * NP64 + 2 * NV) * 4;                 // 63.6 MB

    if (ws_size >= MAIN_NEED) {
        float* u     = ws;
        float* part1 = u     + NU;
        float* part2 = part1 + NP64;
        float* part3 = part2 + NP8;
        float* v1    = part3 + NP8;
        float* v2    = v1    + NV;

        k_uhat<true><<<dim3(64, 16), dim3(320), 0, stream>>>(x, W, u, part1);
        k_vred<<<dim3(256), dim3(320), 0, stream>>>(part1, v1, 64, 0.1f);
        k_route<1><<<dim3(512, 8), dim3(320), 0, stream>>>(u, v1, v1, part2);
        k_vred<<<dim3(256), dim3(320), 0, stream>>>(part2, v2, 8, 1.0f);
        k_route<2><<<dim3(512, 8), dim3(320), 0, stream>>>(u, v1, v2, part3);
        k_vred<<<dim3(256), dim3(320), 0, stream>>>(part3, out, 8, 1.0f);
    } else if (ws_size >= FB_NEED) {
        float* part1 = ws;
        float* partA = part1 + NP64;
        float* partB = partA + NP64;
        float* v1    = partB + NP64;
        float* v2    = v1    + NV;

        k_uhat<false><<<dim3(64, 16), dim3(320), 0, stream>>>(x, W, nullptr, part1);
        k_vred<<<dim3(256), dim3(320), 0, stream>>>(part1, v1, 64, 0.1f);
        k_route_rc<1><<<dim3(64, 16), dim3(320), 0, stream>>>(x, W, v1, v1, partA);
        k_vred<<<dim3(256), dim3(320), 0, stream>>>(partA, v2, 64, 1.0f);
        k_route_rc<2><<<dim3(64, 16), dim3(320), 0, stream>>>(x, W, v1, v2, partB);
        k_vred<<<dim3(256), dim3(320), 0, stream>>>(partB, out, 64, 1.0f);
    }
    // else: ws too small for any path — no safe work possible
}

// Round 7
// 409.873 us; speedup vs baseline: 1.4677x; 1.4677x over previous
//
#include <hip/hip_runtime.h>

#define B_DIM 512
#define R_DIM 1152
#define C_DIM 10
#define CO    160   // C*O = 10*16
#define NCO4  40    // CO/4
#define NB    8     // b's per wave
#define NCH   64    // r-chunks
#define RPC   18    // r's per chunk (64*18 = 1152)

// u4 for one (b,r): outputs co4*4..co4*4+3, reduced over i=8
__device__ __forceinline__ float4 einsum8(const float* w, const float* xr)
{
    float4 acc = make_float4(0.f, 0.f, 0.f, 0.f);
    #pragma unroll
    for (int i = 0; i < 8; ++i) {
        acc.x = fmaf(w[i],      xr[i], acc.x);
        acc.y = fmaf(w[8 + i],  xr[i], acc.y);
        acc.z = fmaf(w[16 + i], xr[i], acc.z);
        acc.w = fmaf(w[24 + i], xr[i], acc.w);
    }
    return acc;
}

// ---------------------------------------------------------------------------
// K1: part[ch][b][co] = sum_{r in chunk} u_hat[b,r,co].  Barrier-free.
// grid (16, 64) x block 256 (4 waves); wave = 8 b's x 18 r's.
// Lanes 0..39 own co4 = lane; lanes 40..63 duplicate co4 = lane-40 (unused).
// ---------------------------------------------------------------------------
__global__ __launch_bounds__(256)
void k_sum(const float* __restrict__ x, const float* __restrict__ W,
           float* __restrict__ part)
{
    const int lane = threadIdx.x & 63;
    const int wv   = __builtin_amdgcn_readfirstlane((int)(threadIdx.x >> 6));
    const int co4  = (lane < NCO4) ? lane : lane - NCO4;
    const int b0   = (blockIdx.x * 4 + wv) * NB;
    const int r0   = blockIdx.y * RPC;

    const float* wp = W + (size_t)r0 * (CO * 8) + co4 * 32;
    float4 sacc[NB];
    #pragma unroll
    for (int i = 0; i < NB; ++i) sacc[i] = make_float4(0.f, 0.f, 0.f, 0.f);

    for (int rr = 0; rr < RPC; ++rr) {
        float w[32];
        #pragma unroll
        for (int k = 0; k < 8; ++k)
            *reinterpret_cast<float4*>(&w[k * 4]) =
                *reinterpret_cast<const float4*>(wp + k * 4);
        #pragma unroll
        for (int bb = 0; bb < NB; ++bb) {
            const float* xq = x + ((size_t)(b0 + bb) * R_DIM + r0 + rr) * 8;
            float xr[8];
            *reinterpret_cast<float4*>(&xr[0]) = *reinterpret_cast<const float4*>(xq);
            *reinterpret_cast<float4*>(&xr[4]) = *reinterpret_cast<const float4*>(xq + 4);
            float4 u4 = einsum8(w, xr);
            sacc[bb].x += u4.x; sacc[bb].y += u4.y;
            sacc[bb].z += u4.z; sacc[bb].w += u4.w;
        }
        wp += CO * 8;
    }
    if (lane < NCO4) {
        #pragma unroll
        for (int bb = 0; bb < NB; ++bb)
            *reinterpret_cast<float4*>(
                part + ((size_t)blockIdx.y * B_DIM + b0 + bb) * CO + co4 * 4) = sacc[bb];
    }
}

// ---------------------------------------------------------------------------
// Routing pass, barrier-free, all-shuffle softmax.  vl = v1 (PASS 1) or
// v1+v2 (PASS 2; b_ij eliminated algebraically: a1+a2 = u.(v1+v2)).
// Quad xor{1,2}: dot over 16 o's -> a[c] per quad.  Butterfly xor{4,8,16,32}:
// each stride-4 class holds exactly one lane per c -> exact max_c / sum_c
// (dup lanes >=40 contribute max-harmless duplicates and e=0 to the sum).
// ---------------------------------------------------------------------------
template<int PASS>
__global__ __launch_bounds__(256)
void k_pass(const float* __restrict__ x, const float* __restrict__ W,
            const float* __restrict__ v1, const float* __restrict__ v2,
            float* __restrict__ part)
{
    const int lane = threadIdx.x & 63;
    const int wv   = __builtin_amdgcn_readfirstlane((int)(threadIdx.x >> 6));
    const int co4  = (lane < NCO4) ? lane : lane - NCO4;
    const int b0   = (blockIdx.x * 4 + wv) * NB;
    const int r0   = blockIdx.y * RPC;

    float4 vl[NB];
    #pragma unroll
    for (int bb = 0; bb < NB; ++bb) {
        float4 a = *reinterpret_cast<const float4*>(
            v1 + (size_t)(b0 + bb) * CO + co4 * 4);
        if constexpr (PASS == 2) {
            float4 b2 = *reinterpret_cast<const float4*>(
                v2 + (size_t)(b0 + bb) * CO + co4 * 4);
            a.x += b2.x; a.y += b2.y; a.z += b2.z; a.w += b2.w;
        }
        vl[bb] = a;
    }

    float4 sacc[NB];
    #pragma unroll
    for (int i = 0; i < NB; ++i) sacc[i] = make_float4(0.f, 0.f, 0.f, 0.f);

    const float* wp = W + (size_t)r0 * (CO * 8) + co4 * 32;
    for (int rr = 0; rr < RPC; ++rr) {
        float w[32];
        #pragma unroll
        for (int k = 0; k < 8; ++k)
            *reinterpret_cast<float4*>(&w[k * 4]) =
                *reinterpret_cast<const float4*>(wp + k * 4);
        #pragma unroll
        for (int bb = 0; bb < NB; ++bb) {
            const float* xq = x + ((size_t)(b0 + bb) * R_DIM + r0 + rr) * 8;
            float xr[8];
            *reinterpret_cast<float4*>(&xr[0]) = *reinterpret_cast<const float4*>(xq);
            *reinterpret_cast<float4*>(&xr[4]) = *reinterpret_cast<const float4*>(xq + 4);
            float4 u4 = einsum8(w, xr);

            float p = u4.x * vl[bb].x + u4.y * vl[bb].y
                    + u4.z * vl[bb].z + u4.w * vl[bb].w;
            p += __shfl_xor(p, 1);
            p += __shfl_xor(p, 2);          // a[c] on all 4 quad lanes

            float m = p;
            m = fmaxf(m, __shfl_xor(m, 4));
            m = fmaxf(m, __shfl_xor(m, 8));
            m = fmaxf(m, __shfl_xor(m, 16));
            m = fmaxf(m, __shfl_xor(m, 32)); // max over all 10 c's

            float e = (lane < NCO4) ? __expf(p - m) : 0.f;
            float Z = e;
            Z += __shfl_xor(Z, 4);
            Z += __shfl_xor(Z, 8);
            Z += __shfl_xor(Z, 16);
            Z += __shfl_xor(Z, 32);          // exact sum_c exp(a_c - m)

            const float cij = e / Z;
            sacc[bb].x += cij * u4.x; sacc[bb].y += cij * u4.y;
            sacc[bb].z += cij * u4.z; sacc[bb].w += cij * u4.w;
        }
        wp += CO * 8;
    }

    if (lane < NCO4) {
        #pragma unroll
        for (int bb = 0; bb < NB; ++bb)
            *reinterpret_cast<float4*>(
                part + ((size_t)blockIdx.y * B_DIM + b0 + bb) * CO + co4 * 4) = sacc[bb];
    }
}

// ---------------------------------------------------------------------------
// Reduce NCH chunk partials -> s, scale, squash over O=16, write dst.
// 81920 outputs: grid 320 x block 256; 16-lane groups = o 0..15 of one (b,c).
// ---------------------------------------------------------------------------
__global__ __launch_bounds__(256)
void k_vred(const float* __restrict__ part, float* __restrict__ dst,
            int nchunk, float scale)
{
    const int idx = blockIdx.x * 256 + threadIdx.x;
    const int b = idx / CO, co = idx % CO;
    float s = 0.f;
    for (int k = 0; k < nchunk; ++k)
        s += part[((size_t)k * B_DIM + b) * CO + co];
    s *= scale;
    float sq = s * s;
    sq += __shfl_xor(sq, 1);
    sq += __shfl_xor(sq, 2);
    sq += __shfl_xor(sq, 4);
    sq += __shfl_xor(sq, 8);
    float v = s * (sq / (1.f + sq)) / sqrtf(sq + 1e-8f);
    dst[idx] = v;
}

// ---------------------------------------------------------------------------
extern "C" void kernel_launch(void* const* d_in, const int* in_sizes, int n_in,
                              void* d_out, int out_size, void* d_ws, size_t ws_size,
                              hipStream_t stream)
{
    const float* x = (const float*)d_in[0];   // [512,1152,8]
    const float* W = (const float*)d_in[1];   // [1,1152,10,16,8]
    float* out = (float*)d_out;               // [512,10,16]
    float* ws  = (float*)d_ws;

    const size_t NP = (size_t)NCH * B_DIM * CO;   // 5,242,880 fl per partial
    const size_t NV = (size_t)B_DIM * CO;         // 81,920 fl per v
    if (ws_size < (3 * NP + 2 * NV) * 4) return;  // 63.6 MB (proven to fit)

    float* part1 = ws;
    float* part2 = part1 + NP;
    float* part3 = part2 + NP;
    float* v1    = part3 + NP;
    float* v2    = v1    + NV;

    const dim3 G(16, NCH), T(256), GV(320), TV(256);
    k_sum    <<<G, T, 0, stream>>>(x, W, part1);
    k_vred   <<<GV, TV, 0, stream>>>(part1, v1, NCH, 0.1f);
    k_pass<1><<<G, T, 0, stream>>>(x, W, v1, v1, part2);
    k_vred   <<<GV, TV, 0, stream>>>(part2, v2, NCH, 1.0f);
    k_pass<2><<<G, T, 0, stream>>>(x, W, v1, v2, part3);
    k_vred   <<<GV, TV, 0, stream>>>(part3, out, NCH, 1.0f);
}